// Round 16
// baseline (29.882 us; speedup 1.0000x reference)
//
#include <hip/hip_runtime.h>

#define SR   9
#define SD   19
#define TW   16                 // tile width (pixels)
#define TH   6                  // tile height (pixels)
#define LW   (TW + 2*SR)        // 34 staged cols
#define LH   (TH + 2*SR)        // 24 staged rows
#define LS   42                 // LDS row stride; odd mod-32 spread
#define IMG  192
#define NPIX (IMG*IMG)

// Block = 384 threads = 6 waves: 48 pixel-pair slots x 8 dy-groups.
// Grid 12x32x2 = 768 blocks = exactly 3/CU.
// r13-r15 lessons: VALU-saturated at ~9.5 emitted ops/px-tap with ~1.6us/iter
// of stall (VGPR=36 starved cross-dx ILP; LDS latency inside the dep chain).
// This round: explicit row prefetch (w1 loads issue before w0's dx loop),
// unshifted Estrin cubic (4 shared consts, no per-pixel preamble),
// deterministic 2-op weight (literal VOP2 mul + max-0), VGPR capped at 64
// via __launch_bounds__(384,8) so all 3 blocks/CU stay resident.
__global__ __launch_bounds__(384, 8) void ms_iter(const float* __restrict__ in,
                                                  float* __restrict__ out) {
    __shared__ __align__(16) float tile[LH * LS];
    __shared__ float4 part[8][48];

    const int b   = blockIdx.z;
    const int bx0 = blockIdx.x * TW;
    const int by0 = blockIdx.y * TH;
    const float* __restrict__ img = in + b * NPIX;

    const int tid = threadIdx.x;      // 0..383
    const int tz  = tid / 48;         // 0..7   dy group
    const int s   = tid - 48 * tz;    // 0..47  pixel-pair slot
    const int tx  = s & 7;            // pair col
    const int ty  = s >> 3;           // pixel row 0..5

    // stage padded tile (replication pad via clamp)
    for (int i = tid; i < LH * LW; i += 384) {
        int r  = i / LW, c = i - r * LW;
        int gy = min(max(by0 + r - SR, 0), IMG - 1);
        int gx = min(max(bx0 + c - SR, 0), IMG - 1);
        tile[r * LS + c] = img[gy * IMG + gx];
    }
    __syncthreads();

    // spatial-x factor exp(-(dx-9)^2/144) (literals in VOP2 muls)
    constexpr float CX[SD] = {
        0.5697829f, 0.6411806f, 0.7115726f, 0.7788008f, 0.8406238f,
        0.8948393f, 0.9394131f, 0.9726045f, 0.9930797f, 1.0000000f,
        0.9930797f, 0.9726045f, 0.9394131f, 0.8948393f, 0.8406238f,
        0.7788008f, 0.7115726f, 0.6411806f, 0.5697829f
    };
    // cubic for A*exp(-2t)-B on t in [0,1]; |err|<1.3e-4, monotone decreasing
    const float a3 = -0.8285240f, a2 = 1.5534825f;
    const float a1 = -1.5923197f, a0 = 0.3138366f;

    const int   x0 = 2 * tx;
    const float cA = tile[(ty + SR) * LS + x0 + SR];
    const float cB = tile[(ty + SR) * LS + x0 + SR + 1];

    // dy rows per tz: {3,3,3,2,2,2,2,2}; only wave 2 mixes 3|2
    const int beg = (tz < 3) ? 3 * tz : (9 + 2 * (tz - 3));
    const int nr  = (tz < 3) ? 3 : 2;

    float numA = 0.f, denA = 0.f, numB = 0.f, denB = 0.f;
    float w0[20], w1[20];

    auto load_row = [&](float* w, int dy) {
        const float2* r2 = reinterpret_cast<const float2*>(&tile[(ty + dy) * LS + x0]);
#pragma unroll
        for (int j = 0; j < 10; ++j) { float2 v = r2[j]; w[2*j] = v.x; w[2*j+1] = v.y; }
    };

    auto compute = [&](const float* w, int dy) {
        const float ft = (float)(dy - SR);
        const float fy = __builtin_amdgcn_exp2f(ft * ft * -0.010018715f);
        float rnA = 0.f, rdA = 0.f, rnB = 0.f, rdB = 0.f;
#pragma unroll
        for (int dx = 0; dx < SD; ++dx) {
            float nA = w[dx], nB = w[dx + 1];
            float dA = cA - nA,  dB = cB - nB;               // 1
            float tA = dA * dA,  tB = dB * dB;               // 1
            float qA = tA * tA,  qB = tB * tB;               // 1 (Estrin)
            float uA = fmaf(a3, tA, a2), uB = fmaf(a3, tB, a2);   // 1
            float vA = fmaf(a1, tA, a0), vB = fmaf(a1, tB, a0);   // 1
            float pA = fmaf(uA, qA, vA), pB = fmaf(uB, qB, vB);   // 1
            float wA = fmaxf(pA * CX[dx], 0.f);              // 2: VOP2 mul + max0
            float wB = fmaxf(pB * CX[dx], 0.f);
            rnA = fmaf(wA, nA, rnA); rdA += wA;              // 2
            rnB = fmaf(wB, nB, rnB); rdB += wB;
        }
        numA = fmaf(fy, rnA, numA); denA = fmaf(fy, rdA, denA);
        numB = fmaf(fy, rnB, numB); denB = fmaf(fy, rdB, denB);
    };

    // software pipeline: next row's LDS loads issue before current dx loop
    load_row(w0, beg);
    load_row(w1, beg + 1);          // every tz has >= 2 rows
    compute(w0, beg);
    if (nr == 3) {
        load_row(w0, beg + 2);
        compute(w1, beg + 1);
        compute(w0, beg + 2);
    } else {
        compute(w1, beg + 1);
    }

    part[tz][s] = make_float4(numA, denA, numB, denB);
    __syncthreads();

    // final combine: 48 threads, one pixel-pair each
    if (tid < 48) {
        float nA = 0.f, dA = 0.f, nB = 0.f, dB = 0.f;
#pragma unroll
        for (int g = 0; g < 8; ++g) {
            float4 v = part[g][tid];
            nA += v.x; dA += v.y; nB += v.z; dB += v.w;
        }
        const float K = 0.04701581f;   // spatial amplitude 1/(SSIGMA*sqrt(2pi))
        float2 o;
        o.x = (K * nA) / (K * dA + 1e-8f);
        o.y = (K * nB) / (K * dB + 1e-8f);
        const int otx = tid & 7, oty = tid >> 3;
        *reinterpret_cast<float2*>(&out[b * NPIX + (by0 + oty) * IMG + bx0 + 2 * otx]) = o;
    }
}

extern "C" void kernel_launch(void* const* d_in, const int* in_sizes, int n_in,
                              void* d_out, int out_size, void* d_ws, size_t ws_size,
                              hipStream_t stream) {
    const float* in  = (const float*)d_in[0];
    float*       out = (float*)d_out;
    float*       ws  = (float*)d_ws;   // needs 2*192*192*4 = 294912 bytes

    dim3 grid(IMG / TW, IMG / TH, 2);   // 12 x 32 x 2 = 768 blocks = 3/CU exact
    dim3 block(384, 1, 1);              // 6 waves

    ms_iter<<<grid, block, 0, stream>>>(in, out);   // iter 1
    ms_iter<<<grid, block, 0, stream>>>(out, ws);   // iter 2
    ms_iter<<<grid, block, 0, stream>>>(ws, out);   // iter 3
}

// Round 17
// 27.105 us; speedup vs baseline: 1.1024x; 1.1024x over previous
//
#include <hip/hip_runtime.h>

#define SR   9
#define SD   19
#define TW   16                 // tile width (pixels)
#define TH   6                  // tile height (pixels)
#define LW   (TW + 2*SR)        // 34 staged cols
#define LH   (TH + 2*SR)        // 24 staged rows
#define LS   42                 // LDS row stride; odd mod-32 spread
#define IMG  192
#define NPIX (IMG*IMG)

// r10 structure verbatim (measured best: 25.3us), single change: weight =
// fmaxf(u*CX_literal, 0) -- two clean VOP2s, no asm SGPR pin, no upper
// clamp (inert: max weight 0.314 < 1; reference has no upper clamp either).
// Block = 384 threads = 6 waves: 48 pixel-pair slots x 8 dy-groups.
// Grid 12x32x2 = 768 blocks = exactly 3/CU.
__global__ __launch_bounds__(384) void ms_iter(const float* __restrict__ in,
                                               float* __restrict__ out) {
    __shared__ __align__(16) float tile[LH * LS];
    __shared__ float4 part[8][48];

    const int b   = blockIdx.z;
    const int bx0 = blockIdx.x * TW;
    const int by0 = blockIdx.y * TH;
    const float* __restrict__ img = in + b * NPIX;

    const int tid = threadIdx.x;      // 0..383
    const int tz  = tid / 48;         // 0..7   dy group
    const int s   = tid - 48 * tz;    // 0..47  pixel-pair slot
    const int tx  = s & 7;            // pair col
    const int ty  = s >> 3;           // pixel row 0..5

    // stage padded tile (replication pad via clamp)
    for (int i = tid; i < LH * LW; i += 384) {
        int r  = i / LW, c = i - r * LW;
        int gy = min(max(by0 + r - SR, 0), IMG - 1);
        int gx = min(max(bx0 + c - SR, 0), IMG - 1);
        tile[r * LS + c] = img[gy * IMG + gx];
    }
    __syncthreads();

    // spatial-x factor exp(-(dx-9)^2/144) (literal operand in VOP2 mul)
    constexpr float CX[SD] = {
        0.5697829f, 0.6411806f, 0.7115726f, 0.7788008f, 0.8406238f,
        0.8948393f, 0.9394131f, 0.9726045f, 0.9930797f, 1.0000000f,
        0.9930797f, 0.9726045f, 0.9394131f, 0.8948393f, 0.8406238f,
        0.7788008f, 0.7115726f, 0.6411806f, 0.5697829f
    };
    const float a3 = -0.8285240f;   // cubic for A*exp(-2t)-B

    const int   x0 = 2 * tx;
    const float cA = tile[(ty + SR) * LS + x0 + SR];
    const float cB = tile[(ty + SR) * LS + x0 + SR + 1];

    // per-pixel shifted coefficients (k = c^2): p(t'+k), t' = n^2 - 2cn
    const float kA = cA * cA, kB = cB * cB;
    const float m2cA = -2.f * cA, m2cB = -2.f * cB;
    const float c2A = kA * -2.4855720f + 1.5534825f;
    const float c2B = kB * -2.4855720f + 1.5534825f;
    const float c1A = (kA * -2.4855720f + 3.1069650f) * kA + -1.5923197f;
    const float c1B = (kB * -2.4855720f + 3.1069650f) * kB + -1.5923197f;
    const float c0A = ((kA * a3 + 1.5534825f) * kA + -1.5923197f) * kA + 0.3138366f;
    const float c0B = ((kB * a3 + 1.5534825f) * kB + -1.5923197f) * kB + 0.3138366f;

    // dy rows per tz: {3,3,3,2,2,2,2,2}; only wave 2 mixes 3|2
    const int beg = (tz < 3) ? 3 * tz : (9 + 2 * (tz - 3));
    const int nr  = (tz < 3) ? 3 : 2;

    float numA = 0.f, denA = 0.f, numB = 0.f, denB = 0.f;
    for (int r = 0; r < nr; ++r) {
        const int   dy = beg + r;
        const float ft = (float)(dy - SR);
        const float fy = __builtin_amdgcn_exp2f(ft * ft * -0.010018715f);

        const float2* r2 = reinterpret_cast<const float2*>(&tile[(ty + dy) * LS + x0]);
        float w[20], h[20];
#pragma unroll
        for (int j = 0; j < 10; ++j) { float2 v = r2[j]; w[2*j] = v.x; w[2*j+1] = v.y; }
#pragma unroll
        for (int j = 0; j < 20; ++j) h[j] = w[j] * w[j];   // n^2, shared by A and B

        float rnA = 0.f, rdA = 0.f, rnB = 0.f, rdB = 0.f;
#pragma unroll
        for (int dx = 0; dx < SD; ++dx) {
            float nA = w[dx], nB = w[dx + 1];
            float tA = fmaf(m2cA, nA, h[dx]);       // t' = n^2 - 2cn
            float tB = fmaf(m2cB, nB, h[dx + 1]);
            float uA = fmaf(a3, tA, c2A);
            float uB = fmaf(a3, tB, c2B);
            uA = fmaf(uA, tA, c1A);   uB = fmaf(uB, tB, c1B);
            uA = fmaf(uA, tA, c0A);   uB = fmaf(uB, tB, c0B);
            float wA = fmaxf(uA * CX[dx], 0.f);     // VOP2 literal mul + max0
            float wB = fmaxf(uB * CX[dx], 0.f);
            rnA = fmaf(wA, nA, rnA); rdA += wA;
            rnB = fmaf(wB, nB, rnB); rdB += wB;
        }
        numA = fmaf(fy, rnA, numA); denA = fmaf(fy, rdA, denA);
        numB = fmaf(fy, rnB, numB); denB = fmaf(fy, rdB, denB);
    }

    part[tz][s] = make_float4(numA, denA, numB, denB);
    __syncthreads();

    // final combine: 48 threads, one pixel-pair each
    if (tid < 48) {
        float nA = 0.f, dA = 0.f, nB = 0.f, dB = 0.f;
#pragma unroll
        for (int g = 0; g < 8; ++g) {
            float4 v = part[g][tid];
            nA += v.x; dA += v.y; nB += v.z; dB += v.w;
        }
        const float K = 0.04701581f;   // spatial amplitude 1/(SSIGMA*sqrt(2pi))
        float2 o;
        o.x = (K * nA) / (K * dA + 1e-8f);
        o.y = (K * nB) / (K * dB + 1e-8f);
        const int otx = tid & 7, oty = tid >> 3;
        *reinterpret_cast<float2*>(&out[b * NPIX + (by0 + oty) * IMG + bx0 + 2 * otx]) = o;
    }
}

extern "C" void kernel_launch(void* const* d_in, const int* in_sizes, int n_in,
                              void* d_out, int out_size, void* d_ws, size_t ws_size,
                              hipStream_t stream) {
    const float* in  = (const float*)d_in[0];
    float*       out = (float*)d_out;
    float*       ws  = (float*)d_ws;   // needs 2*192*192*4 = 294912 bytes

    dim3 grid(IMG / TW, IMG / TH, 2);   // 12 x 32 x 2 = 768 blocks = 3/CU exact
    dim3 block(384, 1, 1);              // 6 waves

    ms_iter<<<grid, block, 0, stream>>>(in, out);   // iter 1
    ms_iter<<<grid, block, 0, stream>>>(out, ws);   // iter 2
    ms_iter<<<grid, block, 0, stream>>>(ws, out);   // iter 3
}

// Round 18
// 25.243 us; speedup vs baseline: 1.1837x; 1.0738x over previous
//
#include <hip/hip_runtime.h>

#define SR   9
#define SD   19
#define TW   16                 // tile width (pixels)
#define TH   6                  // tile height (pixels)
#define LW   (TW + 2*SR)        // 34 staged cols
#define LH   (TH + 2*SR)        // 24 staged rows
#define LS   42                 // LDS row stride; odd float2 stride spreads bank pairs
#define IMG  192
#define NPIX (IMG*IMG)

// MEASURED BEST (r10: 25.3us). Block = 384 threads = 6 waves: 48 pixel-pair
// slots x 8 dy-groups; grid 12x32x2 = 768 blocks = exactly 3/CU.
// Range kernel = cubic p(t), t=(c-n)^2 in [0,1]; per-pixel coefficient shift
// by k=c^2 lets t' = n^2-2cn (h=n^2 shared across the A/B pair).
// Weight = clamp(p*cx): cx asm-pinned to SGPR so it folds to ONE
// v_mul_f32 vdst, s, v clamp (VOP3 clamp needs non-literal src; a literal
// form costs 2 ops + a 32-bit literal fetch per use -- measured +1.8us, r17).
__global__ __launch_bounds__(384) void ms_iter(const float* __restrict__ in,
                                               float* __restrict__ out) {
    __shared__ __align__(16) float tile[LH * LS];
    __shared__ float4 part[8][48];

    const int b   = blockIdx.z;
    const int bx0 = blockIdx.x * TW;
    const int by0 = blockIdx.y * TH;
    const float* __restrict__ img = in + b * NPIX;

    const int tid = threadIdx.x;      // 0..383
    const int tz  = tid / 48;         // 0..7   dy group
    const int s   = tid - 48 * tz;    // 0..47  pixel-pair slot
    const int tx  = s & 7;            // pair col
    const int ty  = s >> 3;           // pixel row 0..5

    // stage padded tile (replication pad via clamp)
    for (int i = tid; i < LH * LW; i += 384) {
        int r  = i / LW, c = i - r * LW;
        int gy = min(max(by0 + r - SR, 0), IMG - 1);
        int gx = min(max(bx0 + c - SR, 0), IMG - 1);
        tile[r * LS + c] = img[gy * IMG + gx];
    }
    __syncthreads();

    constexpr float CX[SD] = {
        0.5697829f, 0.6411806f, 0.7115726f, 0.7788008f, 0.8406238f,
        0.8948393f, 0.9394131f, 0.9726045f, 0.9930797f, 1.0000000f,
        0.9930797f, 0.9726045f, 0.9394131f, 0.8948393f, 0.8406238f,
        0.7788008f, 0.7115726f, 0.6411806f, 0.5697829f
    };
    const float a3 = -0.8285240f;   // cubic for A*exp(-2t)-B

    const int   x0 = 2 * tx;
    const float cA = tile[(ty + SR) * LS + x0 + SR];
    const float cB = tile[(ty + SR) * LS + x0 + SR + 1];

    // per-pixel shifted coefficients (k = c^2): p(t'+k), t' = n^2 - 2cn
    const float kA = cA * cA, kB = cB * cB;
    const float m2cA = -2.f * cA, m2cB = -2.f * cB;
    const float c2A = kA * -2.4855720f + 1.5534825f;
    const float c2B = kB * -2.4855720f + 1.5534825f;
    const float c1A = (kA * -2.4855720f + 3.1069650f) * kA + -1.5923197f;
    const float c1B = (kB * -2.4855720f + 3.1069650f) * kB + -1.5923197f;
    const float c0A = ((kA * a3 + 1.5534825f) * kA + -1.5923197f) * kA + 0.3138366f;
    const float c0B = ((kB * a3 + 1.5534825f) * kB + -1.5923197f) * kB + 0.3138366f;

    // dy rows per tz: {3,3,3,2,2,2,2,2}; only wave 2 mixes 3|2
    const int beg = (tz < 3) ? 3 * tz : (9 + 2 * (tz - 3));
    const int nr  = (tz < 3) ? 3 : 2;

    float numA = 0.f, denA = 0.f, numB = 0.f, denB = 0.f;
    for (int r = 0; r < nr; ++r) {
        const int   dy = beg + r;
        const float ft = (float)(dy - SR);
        const float fy = __builtin_amdgcn_exp2f(ft * ft * -0.010018715f);

        const float2* r2 = reinterpret_cast<const float2*>(&tile[(ty + dy) * LS + x0]);
        float w[20], h[20];
#pragma unroll
        for (int j = 0; j < 10; ++j) { float2 v = r2[j]; w[2*j] = v.x; w[2*j+1] = v.y; }
#pragma unroll
        for (int j = 0; j < 20; ++j) h[j] = w[j] * w[j];   // n^2, shared by A and B

        float rnA = 0.f, rdA = 0.f, rnB = 0.f, rdB = 0.f;
#pragma unroll
        for (int dx = 0; dx < SD; ++dx) {
            float cx = CX[dx];
            asm("" : "+s"(cx));           // pin to SGPR: VOP3 mul+clamp, no literal
            float nA = w[dx], nB = w[dx + 1];
            float tA = fmaf(m2cA, nA, h[dx]);       // t' = n^2 - 2cn
            float tB = fmaf(m2cB, nB, h[dx + 1]);
            float uA = fmaf(a3, tA, c2A);
            float uB = fmaf(a3, tB, c2B);
            uA = fmaf(uA, tA, c1A);   uB = fmaf(uB, tB, c1B);
            uA = fmaf(uA, tA, c0A);   uB = fmaf(uB, tB, c0B);
            float wA = fminf(fmaxf(uA * cx, 0.f), 1.f);   // v_mul sgpr,v clamp
            float wB = fminf(fmaxf(uB * cx, 0.f), 1.f);
            rnA = fmaf(wA, nA, rnA); rdA += wA;
            rnB = fmaf(wB, nB, rnB); rdB += wB;
        }
        numA = fmaf(fy, rnA, numA); denA = fmaf(fy, rdA, denA);
        numB = fmaf(fy, rnB, numB); denB = fmaf(fy, rdB, denB);
    }

    part[tz][s] = make_float4(numA, denA, numB, denB);
    __syncthreads();

    // final combine: 48 threads, one pixel-pair each
    if (tid < 48) {
        float nA = 0.f, dA = 0.f, nB = 0.f, dB = 0.f;
#pragma unroll
        for (int g = 0; g < 8; ++g) {
            float4 v = part[g][tid];
            nA += v.x; dA += v.y; nB += v.z; dB += v.w;
        }
        const float K = 0.04701581f;   // spatial amplitude 1/(SSIGMA*sqrt(2pi))
        float2 o;
        o.x = (K * nA) / (K * dA + 1e-8f);
        o.y = (K * nB) / (K * dB + 1e-8f);
        const int otx = tid & 7, oty = tid >> 3;
        *reinterpret_cast<float2*>(&out[b * NPIX + (by0 + oty) * IMG + bx0 + 2 * otx]) = o;
    }
}

extern "C" void kernel_launch(void* const* d_in, const int* in_sizes, int n_in,
                              void* d_out, int out_size, void* d_ws, size_t ws_size,
                              hipStream_t stream) {
    const float* in  = (const float*)d_in[0];
    float*       out = (float*)d_out;
    float*       ws  = (float*)d_ws;   // needs 2*192*192*4 = 294912 bytes

    dim3 grid(IMG / TW, IMG / TH, 2);   // 12 x 32 x 2 = 768 blocks = 3/CU exact
    dim3 block(384, 1, 1);              // 6 waves

    ms_iter<<<grid, block, 0, stream>>>(in, out);   // iter 1
    ms_iter<<<grid, block, 0, stream>>>(out, ws);   // iter 2
    ms_iter<<<grid, block, 0, stream>>>(ws, out);   // iter 3
}